// Round 9
// baseline (18136.392 us; speedup 1.0000x reference)
//
#include <hip/hip_runtime.h>
#include <hip/hip_fp16.h>

#define EDIM 256
#define HDIM 512
#define CDIM 50257

using half2_t = __attribute__((ext_vector_type(2))) _Float16;
using half8_t = __attribute__((ext_vector_type(8))) _Float16;
using float4_t = __attribute__((ext_vector_type(4))) float;

// tanh(x) = 1 - 2/(exp2(2x*log2e)+1): ~5 VALU instrs vs ~30 for tanhf libcall
__device__ __forceinline__ float fast_tanh(float x) {
    float e = __builtin_amdgcn_exp2f(x * 2.8853900817779268f);
    return 1.f - 2.f * __builtin_amdgcn_rcpf(e + 1.f);
}

// ---------------------------------------------------------------------------
// Pack whh (f32 [512][512]) -> f16 granules [g=0..63][t=0..511][8 halves].
// Scan thread t: rg = t>>4 (16-row group), c = t&15 (32-wide k chunk).
// g = s*4 + i (slot s 0..15, granule i 0..3). XOR-SLOT assignment: slot s on
// thread t holds ROW rg*16 + (s ^ c) — every fold level in the scan is a
// plain add with a DPP/swizzle source; after folding all 4 bits of c, lane c
// holds row rg*16+c == tid.
//   granule = whh[rg*16 + (s^c)][c*32 + i*8 + e], e = 0..7.
// slots 0..11 -> register-resident in scan; slots 12..15 -> streamed from LDS.
// ---------------------------------------------------------------------------
__global__ void __launch_bounds__(256) pack_whh(const float* __restrict__ whh,
                                                _Float16* __restrict__ wpack) {
    int idx = blockIdx.x * blockDim.x + threadIdx.x;   // 0..32767
    int g = idx >> 9, t = idx & 511;
    int row = ((t >> 4) << 4) + ((g >> 2) ^ (t & 15));
    int k0 = ((t & 15) << 5) + ((g & 3) << 3);
    const float* src = whh + row * HDIM + k0;
    uint32_t d[4];
#pragma unroll
    for (int q = 0; q < 4; ++q) {
        half2_t p;
        p[0] = (_Float16)src[2 * q];
        p[1] = (_Float16)src[2 * q + 1];
        d[q] = __builtin_bit_cast(uint32_t, p);
    }
    ((uint4*)wpack)[g * 512 + t] = make_uint4(d[0], d[1], d[2], d[3]);
}

// ---------------------------------------------------------------------------
// z[t][r] = dot(wih[r,:], emb[id_t]) + bih[r] + bhh[r]   (fp32, parallel)
// ---------------------------------------------------------------------------
__global__ void __launch_bounds__(256) zker(const int* __restrict__ in_ids,
                                            const int* __restrict__ out_ids,
                                            const float* __restrict__ emb,
                                            const float* __restrict__ enc_wih,
                                            const float* __restrict__ enc_bih,
                                            const float* __restrict__ enc_bhh,
                                            const float* __restrict__ dec_wih,
                                            const float* __restrict__ dec_bih,
                                            const float* __restrict__ dec_bhh,
                                            float* __restrict__ z) {
    int t = blockIdx.x;
    const float *wih, *bih, *bhh;
    int id;
    if (t < 512) {
        wih = enc_wih; bih = enc_bih; bhh = enc_bhh; id = in_ids[t];
    } else {
        wih = dec_wih; bih = dec_bih; bhh = dec_bhh;
        id = (t == 512) ? 1 : out_ids[t - 513];
    }
    __shared__ float x[EDIM];
    x[threadIdx.x] = emb[(long)id * EDIM + threadIdx.x];
    __syncthreads();
#pragma unroll
    for (int rr = 0; rr < 2; ++rr) {
        int r = threadIdx.x + rr * 256;
        const float4* w4 = (const float4*)(wih + r * EDIM);
        float acc = 0.f;
#pragma unroll 8
        for (int k4 = 0; k4 < 64; ++k4) {
            float4 wv = w4[k4];
            acc += wv.x * x[k4 * 4 + 0] + wv.y * x[k4 * 4 + 1] +
                   wv.z * x[k4 * 4 + 2] + wv.w * x[k4 * 4 + 3];
        }
        z[t * HDIM + r] = acc + bih[r] + bhh[r];
    }
}

// ---------------------------------------------------------------------------
// Sequential RNN scan: 1 workgroup, 512 threads (8 waves, 2/SIMD).
// Thread t: rg = t>>4 owns rows [rg*16, +16) (XOR-permuted per slot), c = t&15
// owns k-slice [c*32, +32). Slots 0..11 register-resident (48 uint4), slots
// 12..15 streamed from LDS. Inner product via v_fma_mix_f32 (f16 sources,
// FULL-RATE f32 pipe: 1 MAC/2cyc/lane — measured dot2/pk_fma_f16 are only
// 2 MACs/8cyc on gfx950): written as fmaf((float)w16,(float)h16,acc) which
// LLVM folds to fma_mix. f32 accumulation throughout (better than dot2 path).
// h f16 in LDS, double-buffered, [i][c] granule layout. Folds: 15 single
// DPP-adds (xor1 0xB1, xor2 0x4E, xor8 row_ror:8) + one ds_swizzle xor4.
// Fast inline tanh. One barrier per step.
// ---------------------------------------------------------------------------
__global__ void __launch_bounds__(512, 2) scan_ker(
    const _Float16* __restrict__ wpack,   // [64][512][8] f16, see pack_whh
    const float* __restrict__ z,          // [nsteps][512] f32
    const _Float16* __restrict__ h_init,  // null => zeros; else [512] plain
    _Float16* __restrict__ hs_out,        // null or [nsteps][512] plain
    _Float16* __restrict__ hfin_out,      // null or [512] plain
    int nsteps) {
    __shared__ uint4 wlds[16 * 512];   // 128 KB: streamed slots 12..15
    __shared__ uint4 hbuf4[2][64];     // 2 KB: h granules, layout [i][c]

    const int tid = threadIdx.x;
    const int c = tid & 15;
    // h element OWNED by this thread after folds is h[tid]; its granule
    // g_own = tid>>3 lives at f16 index 128*(g&3) + 8*(g>>2) ([i][c] layout):
    const int g_own = tid >> 3;
    const int hstore = 128 * (g_own & 3) + 8 * (g_own >> 2) + (tid & 7);

    const uint4* wp4 = (const uint4*)wpack;
    uint4 wreg4[48];                   // slots 0..11, 4 granules each
#pragma unroll
    for (int g = 0; g < 48; ++g) wreg4[g] = wp4[g * 512 + tid];
#pragma unroll
    for (int g = 48; g < 64; ++g) wlds[(g - 48) * 512 + tid] = wp4[g * 512 + tid];

    ((_Float16*)hbuf4[0])[hstore] = h_init ? h_init[tid] : (_Float16)0.f;
    __syncthreads();

    int cur = 0;
    for (int t = 0; t < nsteps; ++t) {
        float zv = z[t * HDIM + tid];          // independent: scheduled early
        const uint4* hb = hbuf4[cur];
        half8_t hh0 = __builtin_bit_cast(half8_t, hb[0 * 16 + c]);
        half8_t hh1 = __builtin_bit_cast(half8_t, hb[1 * 16 + c]);
        half8_t hh2 = __builtin_bit_cast(half8_t, hb[2 * 16 + c]);
        half8_t hh3 = __builtin_bit_cast(half8_t, hb[3 * 16 + c]);
        float f[16];

        // 32 v_fma_mix_f32 per slot: f32 accumulate, f16 sources
#define CHAIN(W0, W1, W2, W3, OUT) do {                                       \
        half8_t _w0 = __builtin_bit_cast(half8_t, (W0));                      \
        half8_t _w1 = __builtin_bit_cast(half8_t, (W1));                      \
        half8_t _w2 = __builtin_bit_cast(half8_t, (W2));                      \
        half8_t _w3 = __builtin_bit_cast(half8_t, (W3));                      \
        float _a = 0.f;                                                       \
        _Pragma("unroll")                                                     \
        for (int _e = 0; _e < 8; ++_e) {                                      \
            _a = fmaf((float)_w0[_e], (float)hh0[_e], _a);                    \
            _a = fmaf((float)_w1[_e], (float)hh1[_e], _a);                    \
            _a = fmaf((float)_w2[_e], (float)hh2[_e], _a);                    \
            _a = fmaf((float)_w3[_e], (float)hh3[_e], _a);                    \
        }                                                                     \
        OUT = _a; } while (0)

#pragma unroll
        for (int s = 0; s < 12; ++s)
            CHAIN(wreg4[s * 4 + 0], wreg4[s * 4 + 1],
                  wreg4[s * 4 + 2], wreg4[s * 4 + 3], f[s]);
#pragma unroll
        for (int js = 0; js < 4; ++js) {
            uint4 w0 = wlds[(js * 4 + 0) * 512 + tid];
            uint4 w1 = wlds[(js * 4 + 1) * 512 + tid];
            uint4 w2 = wlds[(js * 4 + 2) * 512 + tid];
            uint4 w3 = wlds[(js * 4 + 3) * 512 + tid];
            CHAIN(w0, w1, w2, w3, f[12 + js]);
        }
#undef CHAIN

        // XOR-butterfly: slot s holds row (s^c); every level a single add.
#define DPPADD(DST, A, B, CTRL) {                                             \
        int _x = __builtin_amdgcn_mov_dpp(__builtin_bit_cast(int, (B)),       \
                                          CTRL, 0xF, 0xF, true);              \
        DST = (A) + __builtin_bit_cast(float, _x); }
        float t0, t2, t4, t6, t8, t10, t12, t14;
        DPPADD(t0,  f[0],  f[1],  0xB1)   // xor1: quad_perm(1,0,3,2)
        DPPADD(t2,  f[2],  f[3],  0xB1)
        DPPADD(t4,  f[4],  f[5],  0xB1)
        DPPADD(t6,  f[6],  f[7],  0xB1)
        DPPADD(t8,  f[8],  f[9],  0xB1)
        DPPADD(t10, f[10], f[11], 0xB1)
        DPPADD(t12, f[12], f[13], 0xB1)
        DPPADD(t14, f[14], f[15], 0xB1)
        float u0, u4, u8, u12;
        DPPADD(u0,  t0,  t2,  0x4E)       // xor2: quad_perm(2,3,0,1)
        DPPADD(u4,  t4,  t6,  0x4E)
        DPPADD(u8,  t8,  t10, 0x4E)
        DPPADD(u12, t12, t14, 0x4E)
        float v0, v4;
        DPPADD(v0, u0, u8,  0x128)        // xor8: row_ror:8 within 16 lanes
        DPPADD(v4, u4, u12, 0x128)
#undef DPPADD
        float sw = __builtin_bit_cast(float, __builtin_amdgcn_ds_swizzle(
                       __builtin_bit_cast(int, v4), 0x101F));  // xor4
        float vfin = v0 + sw;

        float hnew = fast_tanh(vfin + zv);
        _Float16 h16v = (_Float16)hnew;
        ((_Float16*)hbuf4[cur ^ 1])[hstore] = h16v;
        if (hs_out) hs_out[t * HDIM + tid] = h16v;
        if (hfin_out && t == nsteps - 1) hfin_out[tid] = h16v;
        __syncthreads();
        cur ^= 1;
    }
}

// ---------------------------------------------------------------------------
// Convert fc_w f32 -> f16 once
// ---------------------------------------------------------------------------
__global__ void __launch_bounds__(256) cvt_w16(const float* __restrict__ src,
                                               _Float16* __restrict__ dst, long n) {
    long i = ((long)blockIdx.x * 256 + threadIdx.x) * 8;
    if (i + 8 <= n) {
        const float4* s4 = (const float4*)(src + i);
        float4 a = s4[0], b = s4[1];
        half8_t o;
        o[0] = (_Float16)a.x; o[1] = (_Float16)a.y;
        o[2] = (_Float16)a.z; o[3] = (_Float16)a.w;
        o[4] = (_Float16)b.x; o[5] = (_Float16)b.y;
        o[6] = (_Float16)b.z; o[7] = (_Float16)b.w;
        *(half8_t*)(dst + i) = o;
    }
}

// ---------------------------------------------------------------------------
// FC: out[m][n] = sum_k A16[m][k] * B16[n][k] + fc_b[n]
// M=512, N=50257, K=512. f16 MFMA 16x16x32, direct global frags (B is f16).
// ---------------------------------------------------------------------------
__global__ void __launch_bounds__(256) fc_ker16(const _Float16* __restrict__ A,
                                                const _Float16* __restrict__ Bw,
                                                const float* __restrict__ bias,
                                                float* __restrict__ out) {
    int n0 = blockIdx.x * 128, m0 = blockIdx.y * 128;
    int w = threadIdx.x >> 6, l = threadIdx.x & 63;
    int wm = (w >> 1) * 64, wn = (w & 1) * 64;
    int lr = l & 15, lk = (l >> 4) * 8;

    float4_t acc[4][4];
#pragma unroll
    for (int fm = 0; fm < 4; ++fm)
#pragma unroll
        for (int fn = 0; fn < 4; ++fn) acc[fm][fn] = (float4_t){0.f, 0.f, 0.f, 0.f};

    for (int ks = 0; ks < 512; ks += 32) {
        half8_t a[4], b[4];
#pragma unroll
        for (int f = 0; f < 4; ++f) {
            int m = m0 + wm + f * 16 + lr;
            a[f] = *(const half8_t*)(A + (long)m * 512 + ks + lk);
            int n = n0 + wn + f * 16 + lr;
            if (n < CDIM) {
                b[f] = *(const half8_t*)(Bw + (long)n * 512 + ks + lk);
            } else {
#pragma unroll
                for (int e = 0; e < 8; ++e) b[f][e] = (_Float16)0.f;
            }
        }
#pragma unroll
        for (int fm = 0; fm < 4; ++fm)
#pragma unroll
            for (int fn = 0; fn < 4; ++fn)
                acc[fm][fn] = __builtin_amdgcn_mfma_f32_16x16x32_f16(
                    a[fm], b[fn], acc[fm][fn], 0, 0, 0);
    }
#pragma unroll
    for (int fn = 0; fn < 4; ++fn) {
        int n = n0 + wn + fn * 16 + lr;
        if (n >= CDIM) continue;
        float bv = bias[n];
#pragma unroll
        for (int fm = 0; fm < 4; ++fm) {
#pragma unroll
            for (int q = 0; q < 4; ++q) {
                int m = m0 + wm + fm * 16 + (l >> 4) * 4 + q;
                out[(long)m * CDIM + n] = acc[fm][fn][q] + bv;
            }
        }
    }
}

// Fallback FC reading f32 B with inline conversion (if ws too small for f16 B)
__global__ void __launch_bounds__(256) fc_ker(const _Float16* __restrict__ A,
                                              const float* __restrict__ Bw,
                                              const float* __restrict__ bias,
                                              float* __restrict__ out) {
    int n0 = blockIdx.x * 128, m0 = blockIdx.y * 128;
    int w = threadIdx.x >> 6, l = threadIdx.x & 63;
    int wm = (w >> 1) * 64, wn = (w & 1) * 64;
    int lr = l & 15, lk = (l >> 4) * 8;

    float4_t acc[4][4];
#pragma unroll
    for (int fm = 0; fm < 4; ++fm)
#pragma unroll
        for (int fn = 0; fn < 4; ++fn) acc[fm][fn] = (float4_t){0.f, 0.f, 0.f, 0.f};

    for (int ks = 0; ks < 512; ks += 32) {
        half8_t a[4], b[4];
#pragma unroll
        for (int f = 0; f < 4; ++f) {
            int m = m0 + wm + f * 16 + lr;
            a[f] = *(const half8_t*)(A + (long)m * 512 + ks + lk);
            int n = n0 + wn + f * 16 + lr;
            half8_t bb;
            if (n < CDIM) {
                const float4* bp4 = (const float4*)(Bw + (long)n * 512 + ks + lk);
                float4 x0 = bp4[0], x1 = bp4[1];
                bb[0] = (_Float16)x0.x; bb[1] = (_Float16)x0.y;
                bb[2] = (_Float16)x0.z; bb[3] = (_Float16)x0.w;
                bb[4] = (_Float16)x1.x; bb[5] = (_Float16)x1.y;
                bb[6] = (_Float16)x1.z; bb[7] = (_Float16)x1.w;
            } else {
#pragma unroll
                for (int e = 0; e < 8; ++e) bb[e] = (_Float16)0.f;
            }
            b[f] = bb;
        }
#pragma unroll
        for (int fm = 0; fm < 4; ++fm)
#pragma unroll
            for (int fn = 0; fn < 4; ++fn)
                acc[fm][fn] = __builtin_amdgcn_mfma_f32_16x16x32_f16(
                    a[fm], b[fn], acc[fm][fn], 0, 0, 0);
    }
#pragma unroll
    for (int fn = 0; fn < 4; ++fn) {
        int n = n0 + wn + fn * 16 + lr;
        if (n >= CDIM) continue;
        float bv = bias[n];
#pragma unroll
        for (int fm = 0; fm < 4; ++fm) {
#pragma unroll
            for (int q = 0; q < 4; ++q) {
                int m = m0 + wm + fm * 16 + (l >> 4) * 4 + q;
                out[(long)m * CDIM + n] = acc[fm][fn][q] + bv;
            }
        }
    }
}

// ---------------------------------------------------------------------------
// Workspace layout:
//   [0, 2MB)          z  f32 [1024][512]
//   [2MB, 2.5MB)      wpack_enc f16
//   [2.5MB, 3MB)      wpack_dec f16
//   [3MB, 3.5MB)      h16 f16 [512][512]  (decoder hidden states = FC A matrix)
//   [3.5MB, +1KB)     hn16 f16 [512]      (encoder final hidden)
//   [4MB, 4MB+51.5MB) fc_w16 (only if ws_size permits)
// ---------------------------------------------------------------------------
extern "C" void kernel_launch(void* const* d_in, const int* in_sizes, int n_in,
                              void* d_out, int out_size, void* d_ws, size_t ws_size,
                              hipStream_t stream) {
    const int* input_ids  = (const int*)d_in[1];
    const int* output_ids = (const int*)d_in[2];
    const float* emb      = (const float*)d_in[3];
    const float* enc_wih  = (const float*)d_in[4];
    const float* enc_whh  = (const float*)d_in[5];
    const float* enc_bih  = (const float*)d_in[6];
    const float* enc_bhh  = (const float*)d_in[7];
    const float* dec_wih  = (const float*)d_in[8];
    const float* dec_whh  = (const float*)d_in[9];
    const float* dec_bih  = (const float*)d_in[10];
    const float* dec_bhh  = (const float*)d_in[11];
    const float* fc_w     = (const float*)d_in[12];
    const float* fc_b     = (const float*)d_in[13];
    float* out = (float*)d_out;

    char* ws = (char*)d_ws;
    float* z        = (float*)ws;                                  // 2 MB
    _Float16* wpe   = (_Float16*)(ws + (2u << 20));                // 512 KB
    _Float16* wpd   = (_Float16*)(ws + (2u << 20) + (512u << 10)); // 512 KB
    _Float16* h16   = (_Float16*)(ws + (3u << 20));                // 512 KB
    _Float16* hn16  = (_Float16*)(ws + (3u << 20) + (512u << 10)); // 1 KB
    _Float16* fcw16 = (_Float16*)(ws + (4u << 20));                // 51.5 MB

    const long fcw_n = (long)CDIM * HDIM;
    bool use_f16_fc = ws_size >= (size_t)(4u << 20) + (size_t)fcw_n * 2;

    pack_whh<<<128, 256, 0, stream>>>(enc_whh, wpe);
    pack_whh<<<128, 256, 0, stream>>>(dec_whh, wpd);
    if (use_f16_fc) {
        int nb = (int)((fcw_n / 8 + 255) / 256);
        cvt_w16<<<nb, 256, 0, stream>>>(fc_w, fcw16, fcw_n);
    }
    zker<<<1024, 256, 0, stream>>>(input_ids, output_ids, emb,
                                   enc_wih, enc_bih, enc_bhh,
                                   dec_wih, dec_bih, dec_bhh, z);
    // encoder: h starts at 0, produce hn16
    scan_ker<<<1, 512, 0, stream>>>(wpe, z, nullptr, nullptr, hn16, 512);
    // decoder: h starts at hn16, produce all 512 hidden states
    scan_ker<<<1, 512, 0, stream>>>(wpd, z + 512 * HDIM, hn16, h16, nullptr, 512);
    if (use_f16_fc)
        fc_ker16<<<dim3((CDIM + 127) / 128, 4), 256, 0, stream>>>(h16, fcw16, fc_b, out);
    else
        fc_ker<<<dim3((CDIM + 127) / 128, 4), 256, 0, stream>>>(h16, fc_w, fc_b, out);
}

// Round 10
// 1677.744 us; speedup vs baseline: 10.8100x; 10.8100x over previous
//
#include <hip/hip_runtime.h>
#include <hip/hip_fp16.h>

#define EDIM 256
#define HDIM 512
#define CDIM 50257

using half2_t = __attribute__((ext_vector_type(2))) _Float16;
using half8_t = __attribute__((ext_vector_type(8))) _Float16;
using float4_t = __attribute__((ext_vector_type(4))) float;

__device__ __forceinline__ float dot2(uint32_t w, uint32_t h, float acc) {
    return __builtin_amdgcn_fdot2(__builtin_bit_cast(half2_t, w),
                                  __builtin_bit_cast(half2_t, h), acc, false);
}

// tanh(x) = 1 - 2/(exp2(2x*log2e)+1): ~5 VALU instrs vs ~30 for tanhf libcall
__device__ __forceinline__ float fast_tanh(float x) {
    float e = __builtin_amdgcn_exp2f(x * 2.8853900817779268f);
    return 1.f - 2.f * __builtin_amdgcn_rcpf(e + 1.f);
}

// ---------------------------------------------------------------------------
// PREP kernel: fuses 4 independent jobs into one launch (they ran as 4
// serial launches before; all 255 idle CUs now overlap them):
//   blocks [0,128)              : pack enc_whh -> wpe
//   blocks [128,256)            : pack dec_whh -> wpd
//   blocks [256, 256+nb_cvt)    : fc_w f32 -> f16
//   blocks [256+nb_cvt, +1024)  : zker (z precompute)
//
// pack layout (R6-validated): scan thread t: rg=t>>4 (16-row group), c=t&15
// (32-wide k chunk). g = jr*4 + i: granule = whh[rg*16+jr][c*32+i*8+e].
// jr 0..11 register-resident in scan; jr 12..15 streamed from LDS.
// ---------------------------------------------------------------------------
__global__ void __launch_bounds__(256) prep_ker(
    const float* __restrict__ enc_whh, const float* __restrict__ dec_whh,
    _Float16* __restrict__ wpe, _Float16* __restrict__ wpd,
    const float* __restrict__ fc_w, _Float16* __restrict__ fcw16,
    long fcw_n, int nb_cvt,
    const int* __restrict__ in_ids, const int* __restrict__ out_ids,
    const float* __restrict__ emb,
    const float* __restrict__ enc_wih, const float* __restrict__ enc_bih,
    const float* __restrict__ enc_bhh,
    const float* __restrict__ dec_wih, const float* __restrict__ dec_bih,
    const float* __restrict__ dec_bhh,
    float* __restrict__ z) {
    __shared__ float x[EDIM];
    int b = blockIdx.x;
    if (b < 256) {
        // ---- pack_whh ----
        const float* whh = (b < 128) ? enc_whh : dec_whh;
        _Float16* wpack  = (b < 128) ? wpe : wpd;
        int idx = (b & 127) * 256 + threadIdx.x;       // 0..32767
        int g = idx >> 9, t = idx & 511;
        int jr = g >> 2, i = g & 3;
        int row = ((t >> 4) << 4) + jr;
        int k0 = ((t & 15) << 5) + (i << 3);
        const float* src = whh + row * HDIM + k0;
        uint32_t d[4];
#pragma unroll
        for (int q = 0; q < 4; ++q) {
            half2_t p;
            p[0] = (_Float16)src[2 * q];
            p[1] = (_Float16)src[2 * q + 1];
            d[q] = __builtin_bit_cast(uint32_t, p);
        }
        ((uint4*)wpack)[g * 512 + t] = make_uint4(d[0], d[1], d[2], d[3]);
    } else if (b < 256 + nb_cvt) {
        // ---- cvt fc_w -> f16 ----
        long i = ((long)(b - 256) * 256 + threadIdx.x) * 8;
        if (i + 8 <= fcw_n) {
            const float4* s4 = (const float4*)(fc_w + i);
            float4 a = s4[0], bb = s4[1];
            half8_t o;
            o[0] = (_Float16)a.x;  o[1] = (_Float16)a.y;
            o[2] = (_Float16)a.z;  o[3] = (_Float16)a.w;
            o[4] = (_Float16)bb.x; o[5] = (_Float16)bb.y;
            o[6] = (_Float16)bb.z; o[7] = (_Float16)bb.w;
            *(half8_t*)(fcw16 + i) = o;
        }
    } else {
        // ---- zker: z[t][r] = wih[r,:]·emb[id_t] + bih[r] + bhh[r] ----
        int t = b - 256 - nb_cvt;                      // 0..1023
        const float *wih, *bih, *bhh;
        int id;
        if (t < 512) {
            wih = enc_wih; bih = enc_bih; bhh = enc_bhh; id = in_ids[t];
        } else {
            wih = dec_wih; bih = dec_bih; bhh = dec_bhh;
            id = (t == 512) ? 1 : out_ids[t - 513];
        }
        x[threadIdx.x] = emb[(long)id * EDIM + threadIdx.x];
        __syncthreads();
#pragma unroll
        for (int rr = 0; rr < 2; ++rr) {
            int r = threadIdx.x + rr * 256;
            const float4* w4 = (const float4*)(wih + r * EDIM);
            float acc = 0.f;
#pragma unroll 8
            for (int k4 = 0; k4 < 64; ++k4) {
                float4 wv = w4[k4];
                acc += wv.x * x[k4 * 4 + 0] + wv.y * x[k4 * 4 + 1] +
                       wv.z * x[k4 * 4 + 2] + wv.w * x[k4 * 4 + 3];
            }
            z[t * HDIM + r] = acc + bih[r] + bhh[r];
        }
    }
}

// ---------------------------------------------------------------------------
// Sequential RNN scan (EXACT R6 structure — best validated: 709 us/scan).
// 1 workgroup, 512 threads (8 waves, 2/SIMD).
// Thread t: rg = t>>4 owns rows [rg*16, +16), c = t&15 owns k-slice
// [c*32, +32). 12/16 rows register-resident (192 words arch+AGPR), 4/16
// streamed from LDS (128 KB). h f16 in LDS, double-buffered, [i][c] granule
// layout (2-way bank alias = free). Fold 15 levels: xor1/xor2 DPP quad_perm,
// xor8 DPP row_ror:8, xor4 ds_swizzle. Fast inline tanh. 1 barrier/step.
// Known-wall notes: all vector MAC paths cap at 128 MAC/cyc/CU on gfx950
// (dot2@4cyc == fp32 peak rate); MAC floor 2048 cyc/step; this runs ~3325.
// ---------------------------------------------------------------------------
__global__ void __launch_bounds__(512, 2) scan_ker(
    const _Float16* __restrict__ wpack,   // [64][512][8] f16, see prep_ker
    const float* __restrict__ z,          // [nsteps][512] f32
    const _Float16* __restrict__ h_init,  // null => zeros; else [512] plain
    _Float16* __restrict__ hs_out,        // null or [nsteps][512] plain
    _Float16* __restrict__ hfin_out,      // null or [512] plain
    int nsteps) {
    __shared__ uint4 wlds[16 * 512];   // 128 KB: streamed rows jr=12..15
    __shared__ uint4 hbuf4[2][64];     // 2 KB: h granules, layout [i][c]

    const int tid = threadIdx.x;
    const int c = tid & 15;
    const int g_own = tid >> 3;
    const int hstore = 128 * (g_own & 3) + 8 * (g_own >> 2) + (tid & 7);

    const uint4* wp4 = (const uint4*)wpack;
    uint32_t wreg[192];                // rows jr=0..11 (4 granules each)
#pragma unroll
    for (int g = 0; g < 48; ++g) {
        uint4 v = wp4[g * 512 + tid];
        wreg[g * 4 + 0] = v.x; wreg[g * 4 + 1] = v.y;
        wreg[g * 4 + 2] = v.z; wreg[g * 4 + 3] = v.w;
    }
#pragma unroll
    for (int g = 48; g < 64; ++g) wlds[(g - 48) * 512 + tid] = wp4[g * 512 + tid];

    ((_Float16*)hbuf4[0])[hstore] = h_init ? h_init[tid] : (_Float16)0.f;
    __syncthreads();

    _Float16 hlast = (_Float16)0.f;
    int cur = 0;
    for (int t = 0; t < nsteps; ++t) {
        float zv = z[t * HDIM + tid];          // independent: scheduled early
        const uint4* hb = hbuf4[cur];
        float acc[16];
#pragma unroll
        for (int r = 0; r < 16; ++r) acc[r] = 0.f;
#pragma unroll
        for (int i = 0; i < 4; ++i) {
            uint4 hg = hb[i * 16 + c];         // h[k = c*32+i*8 .. +8)
#pragma unroll
            for (int jr = 0; jr < 12; ++jr) {
                acc[jr] = dot2(wreg[(jr * 4 + i) * 4 + 0], hg.x, acc[jr]);
                acc[jr] = dot2(wreg[(jr * 4 + i) * 4 + 1], hg.y, acc[jr]);
                acc[jr] = dot2(wreg[(jr * 4 + i) * 4 + 2], hg.z, acc[jr]);
                acc[jr] = dot2(wreg[(jr * 4 + i) * 4 + 3], hg.w, acc[jr]);
            }
#pragma unroll
            for (int js = 0; js < 4; ++js) {
                uint4 w = wlds[(js * 4 + i) * 512 + tid];
                acc[12 + js] = dot2(w.x, hg.x, acc[12 + js]);
                acc[12 + js] = dot2(w.y, hg.y, acc[12 + js]);
                acc[12 + js] = dot2(w.z, hg.z, acc[12 + js]);
                acc[12 + js] = dot2(w.w, hg.w, acc[12 + js]);
            }
        }
        // Fold 16 accs over the 4 bits of c; lane c ends with row rg*16+c.
        float s, keep;
#define FOLD_DPP(aL, aH, bit, ctrl, dst)                                      \
        s = (c & bit) ? (aL) : (aH);                                          \
        s = __builtin_bit_cast(float, __builtin_amdgcn_mov_dpp(               \
                __builtin_bit_cast(int, s), ctrl, 0xF, 0xF, true));           \
        keep = (c & bit) ? (aH) : (aL);                                       \
        dst = keep + s;
#define FOLD_SWZ(aL, aH, bit, pat, dst)                                       \
        s = (c & bit) ? (aL) : (aH);                                          \
        s = __builtin_bit_cast(float, __builtin_amdgcn_ds_swizzle(            \
                __builtin_bit_cast(int, s), pat));                            \
        keep = (c & bit) ? (aH) : (aL);                                       \
        dst = keep + s;
        float b0, b1, b2, b3, b4, b5, b6, b7, d0, d1, d2, d3, e0, e1, v;
        FOLD_DPP(acc[0],  acc[1],  1, 0xB1, b0)   // xor1: quad_perm(1,0,3,2)
        FOLD_DPP(acc[2],  acc[3],  1, 0xB1, b1)
        FOLD_DPP(acc[4],  acc[5],  1, 0xB1, b2)
        FOLD_DPP(acc[6],  acc[7],  1, 0xB1, b3)
        FOLD_DPP(acc[8],  acc[9],  1, 0xB1, b4)
        FOLD_DPP(acc[10], acc[11], 1, 0xB1, b5)
        FOLD_DPP(acc[12], acc[13], 1, 0xB1, b6)
        FOLD_DPP(acc[14], acc[15], 1, 0xB1, b7)
        FOLD_DPP(b0, b1, 2, 0x4E, d0)   // xor2: quad_perm(2,3,0,1)
        FOLD_DPP(b2, b3, 2, 0x4E, d1)
        FOLD_DPP(b4, b5, 2, 0x4E, d2)
        FOLD_DPP(b6, b7, 2, 0x4E, d3)
        FOLD_DPP(d0, d2, 8, 0x128, e0)  // xor8: row_ror:8 within 16 lanes
        FOLD_DPP(d1, d3, 8, 0x128, e1)
        FOLD_SWZ(e0, e1, 4, 0x101F, v)  // xor4 via ds_swizzle
#undef FOLD_DPP
#undef FOLD_SWZ
        float hnew = fast_tanh(v + zv);
        _Float16 h16v = (_Float16)hnew;
        ((_Float16*)hbuf4[cur ^ 1])[hstore] = h16v;
        if (hs_out) hs_out[t * HDIM + tid] = h16v;
        hlast = h16v;
        __syncthreads();
        cur ^= 1;
    }
    if (hfin_out) hfin_out[tid] = hlast;
}

// ---------------------------------------------------------------------------
// FC: out[m][n] = sum_k A16[m][k] * B16[n][k] + fc_b[n]
// M=512, N=50257, K=512. f16 MFMA 16x16x32, direct global frags (B is f16).
// ---------------------------------------------------------------------------
__global__ void __launch_bounds__(256) fc_ker16(const _Float16* __restrict__ A,
                                                const _Float16* __restrict__ Bw,
                                                const float* __restrict__ bias,
                                                float* __restrict__ out) {
    int n0 = blockIdx.x * 128, m0 = blockIdx.y * 128;
    int w = threadIdx.x >> 6, l = threadIdx.x & 63;
    int wm = (w >> 1) * 64, wn = (w & 1) * 64;
    int lr = l & 15, lk = (l >> 4) * 8;

    float4_t acc[4][4];
#pragma unroll
    for (int fm = 0; fm < 4; ++fm)
#pragma unroll
        for (int fn = 0; fn < 4; ++fn) acc[fm][fn] = (float4_t){0.f, 0.f, 0.f, 0.f};

    for (int ks = 0; ks < 512; ks += 32) {
        half8_t a[4], b[4];
#pragma unroll
        for (int f = 0; f < 4; ++f) {
            int m = m0 + wm + f * 16 + lr;
            a[f] = *(const half8_t*)(A + (long)m * 512 + ks + lk);
            int n = n0 + wn + f * 16 + lr;
            if (n < CDIM) {
                b[f] = *(const half8_t*)(Bw + (long)n * 512 + ks + lk);
            } else {
#pragma unroll
                for (int e = 0; e < 8; ++e) b[f][e] = (_Float16)0.f;
            }
        }
#pragma unroll
        for (int fm = 0; fm < 4; ++fm)
#pragma unroll
            for (int fn = 0; fn < 4; ++fn)
                acc[fm][fn] = __builtin_amdgcn_mfma_f32_16x16x32_f16(
                    a[fm], b[fn], acc[fm][fn], 0, 0, 0);
    }
#pragma unroll
    for (int fn = 0; fn < 4; ++fn) {
        int n = n0 + wn + fn * 16 + lr;
        if (n >= CDIM) continue;
        float bv = bias[n];
#pragma unroll
        for (int fm = 0; fm < 4; ++fm) {
#pragma unroll
            for (int q = 0; q < 4; ++q) {
                int m = m0 + wm + fm * 16 + (l >> 4) * 4 + q;
                out[(long)m * CDIM + n] = acc[fm][fn][q] + bv;
            }
        }
    }
}

// Fallback FC reading f32 B with inline conversion (if ws too small for f16 B)
__global__ void __launch_bounds__(256) fc_ker(const _Float16* __restrict__ A,
                                              const float* __restrict__ Bw,
                                              const float* __restrict__ bias,
                                              float* __restrict__ out) {
    int n0 = blockIdx.x * 128, m0 = blockIdx.y * 128;
    int w = threadIdx.x >> 6, l = threadIdx.x & 63;
    int wm = (w >> 1) * 64, wn = (w & 1) * 64;
    int lr = l & 15, lk = (l >> 4) * 8;

    float4_t acc[4][4];
#pragma unroll
    for (int fm = 0; fm < 4; ++fm)
#pragma unroll
        for (int fn = 0; fn < 4; ++fn) acc[fm][fn] = (float4_t){0.f, 0.f, 0.f, 0.f};

    for (int ks = 0; ks < 512; ks += 32) {
        half8_t a[4], b[4];
#pragma unroll
        for (int f = 0; f < 4; ++f) {
            int m = m0 + wm + f * 16 + lr;
            a[f] = *(const half8_t*)(A + (long)m * 512 + ks + lk);
            int n = n0 + wn + f * 16 + lr;
            half8_t bb;
            if (n < CDIM) {
                const float4* bp4 = (const float4*)(Bw + (long)n * 512 + ks + lk);
                float4 x0 = bp4[0], x1 = bp4[1];
                bb[0] = (_Float16)x0.x; bb[1] = (_Float16)x0.y;
                bb[2] = (_Float16)x0.z; bb[3] = (_Float16)x0.w;
                bb[4] = (_Float16)x1.x; bb[5] = (_Float16)x1.y;
                bb[6] = (_Float16)x1.z; bb[7] = (_Float16)x1.w;
            } else {
#pragma unroll
                for (int e = 0; e < 8; ++e) bb[e] = (_Float16)0.f;
            }
            b[f] = bb;
        }
#pragma unroll
        for (int fm = 0; fm < 4; ++fm)
#pragma unroll
            for (int fn = 0; fn < 4; ++fn)
                acc[fm][fn] = __builtin_amdgcn_mfma_f32_16x16x32_f16(
                    a[fm], b[fn], acc[fm][fn], 0, 0, 0);
    }
#pragma unroll
    for (int fn = 0; fn < 4; ++fn) {
        int n = n0 + wn + fn * 16 + lr;
        if (n >= CDIM) continue;
        float bv = bias[n];
#pragma unroll
        for (int fm = 0; fm < 4; ++fm) {
#pragma unroll
            for (int q = 0; q < 4; ++q) {
                int m = m0 + wm + fm * 16 + (l >> 4) * 4 + q;
                out[(long)m * CDIM + n] = acc[fm][fn][q] + bv;
            }
        }
    }
}

// ---------------------------------------------------------------------------
// Workspace layout:
//   [0, 2MB)          z  f32 [1024][512]
//   [2MB, 2.5MB)      wpack_enc f16
//   [2.5MB, 3MB)      wpack_dec f16
//   [3MB, 3.5MB)      h16 f16 [512][512]  (decoder hidden states = FC A matrix)
//   [3.5MB, +1KB)     hn16 f16 [512]      (encoder final hidden)
//   [4MB, 4MB+51.5MB) fc_w16 (only if ws_size permits)
// ---------------------------------------------------------------------------
extern "C" void kernel_launch(void* const* d_in, const int* in_sizes, int n_in,
                              void* d_out, int out_size, void* d_ws, size_t ws_size,
                              hipStream_t stream) {
    const int* input_ids  = (const int*)d_in[1];
    const int* output_ids = (const int*)d_in[2];
    const float* emb      = (const float*)d_in[3];
    const float* enc_wih  = (const float*)d_in[4];
    const float* enc_whh  = (const float*)d_in[5];
    const float* enc_bih  = (const float*)d_in[6];
    const float* enc_bhh  = (const float*)d_in[7];
    const float* dec_wih  = (const float*)d_in[8];
    const float* dec_whh  = (const float*)d_in[9];
    const float* dec_bih  = (const float*)d_in[10];
    const float* dec_bhh  = (const float*)d_in[11];
    const float* fc_w     = (const float*)d_in[12];
    const float* fc_b     = (const float*)d_in[13];
    float* out = (float*)d_out;

    char* ws = (char*)d_ws;
    float* z        = (float*)ws;                                  // 2 MB
    _Float16* wpe   = (_Float16*)(ws + (2u << 20));                // 512 KB
    _Float16* wpd   = (_Float16*)(ws + (2u << 20) + (512u << 10)); // 512 KB
    _Float16* h16   = (_Float16*)(ws + (3u << 20));                // 512 KB
    _Float16* hn16  = (_Float16*)(ws + (3u << 20) + (512u << 10)); // 1 KB
    _Float16* fcw16 = (_Float16*)(ws + (4u << 20));                // 51.5 MB

    const long fcw_n = (long)CDIM * HDIM;
    bool use_f16_fc = ws_size >= (size_t)(4u << 20) + (size_t)fcw_n * 2;
    int nb_cvt = use_f16_fc ? (int)((fcw_n / 8 + 255) / 256) : 0;

    // one fused prep launch: pack enc + pack dec + cvt fc_w + zker
    prep_ker<<<256 + nb_cvt + 1024, 256, 0, stream>>>(
        enc_whh, dec_whh, wpe, wpd,
        fc_w, fcw16, fcw_n, nb_cvt,
        input_ids, output_ids, emb,
        enc_wih, enc_bih, enc_bhh,
        dec_wih, dec_bih, dec_bhh, z);
    // encoder: h starts at 0, produce hn16
    scan_ker<<<1, 512, 0, stream>>>(wpe, z, nullptr, nullptr, hn16, 512);
    // decoder: h starts at hn16, produce all 512 hidden states
    scan_ker<<<1, 512, 0, stream>>>(wpd, z + 512 * HDIM, hn16, h16, nullptr, 512);
    if (use_f16_fc)
        fc_ker16<<<dim3((CDIM + 127) / 128, 4), 256, 0, stream>>>(h16, fcw16, fc_b, out);
    else
        fc_ker<<<dim3((CDIM + 127) / 128, 4), 256, 0, stream>>>(h16, fc_w, fc_b, out);
}

// Round 11
// 1641.103 us; speedup vs baseline: 11.0513x; 1.0223x over previous
//
#include <hip/hip_runtime.h>
#include <hip/hip_fp16.h>

#define EDIM 256
#define HDIM 512
#define CDIM 50257
#define NT_FC 197                 // ceil(50257 / 256) n-tiles
#define NJOBS (NT_FC * 4)         // x 4 m-tiles

using half2_t = __attribute__((ext_vector_type(2))) _Float16;
using half8_t = __attribute__((ext_vector_type(8))) _Float16;
using float4_t = __attribute__((ext_vector_type(4))) float;

__device__ __forceinline__ float dot2(uint32_t w, uint32_t h, float acc) {
    return __builtin_amdgcn_fdot2(__builtin_bit_cast(half2_t, w),
                                  __builtin_bit_cast(half2_t, h), acc, false);
}

// tanh(x) = 1 - 2/(exp2(2x*log2e)+1)
__device__ __forceinline__ float fast_tanh(float x) {
    float e = __builtin_amdgcn_exp2f(x * 2.8853900817779268f);
    return 1.f - 2.f * __builtin_amdgcn_rcpf(e + 1.f);
}

// ---------------------------------------------------------------------------
// R6-validated scan body (709-712 us/scan, 5 rounds stable). Thread t:
// rg = t>>4 owns rows [rg*16,+16), c = t&15 owns k-slice [c*32,+32).
// 12/16 rows register-resident, 4/16 streamed from LDS (128 KB). h f16 in
// LDS, double-buffered, [i][c] granule layout. Folds: xor1/xor2 DPP
// quad_perm, xor8 DPP row_ror:8, xor4 ds_swizzle. One barrier/step.
// NEW: optional progress publication every 128 steps (agent-scope) so
// consumer blocks in the SAME kernel can start FC on finished h16 rows.
// ---------------------------------------------------------------------------
__device__ __forceinline__ void scan_body(
    const _Float16* __restrict__ wpack, const float* __restrict__ z,
    const _Float16* __restrict__ h_init, _Float16* __restrict__ hs_out,
    _Float16* __restrict__ hfin_out, int* prog, int nsteps,
    uint4* wlds, uint4* hbuf4) {
    const int tid = threadIdx.x;
    const int c = tid & 15;
    const int g_own = tid >> 3;
    const int hstore = 128 * (g_own & 3) + 8 * (g_own >> 2) + (tid & 7);

    const uint4* wp4 = (const uint4*)wpack;
    uint32_t wreg[192];                // rows jr=0..11
#pragma unroll
    for (int g = 0; g < 48; ++g) {
        uint4 v = wp4[g * 512 + tid];
        wreg[g * 4 + 0] = v.x; wreg[g * 4 + 1] = v.y;
        wreg[g * 4 + 2] = v.z; wreg[g * 4 + 3] = v.w;
    }
#pragma unroll
    for (int g = 48; g < 64; ++g) wlds[(g - 48) * 512 + tid] = wp4[g * 512 + tid];

    ((_Float16*)hbuf4)[hstore] = h_init ? h_init[tid] : (_Float16)0.f;
    __syncthreads();

    _Float16 hlast = (_Float16)0.f;
    int cur = 0;
    for (int t = 0; t < nsteps; ++t) {
        float zv = z[t * HDIM + tid];
        const uint4* hb = hbuf4 + cur * 64;
        float acc[16];
#pragma unroll
        for (int r = 0; r < 16; ++r) acc[r] = 0.f;
#pragma unroll
        for (int i = 0; i < 4; ++i) {
            uint4 hg = hb[i * 16 + c];
#pragma unroll
            for (int jr = 0; jr < 12; ++jr) {
                acc[jr] = dot2(wreg[(jr * 4 + i) * 4 + 0], hg.x, acc[jr]);
                acc[jr] = dot2(wreg[(jr * 4 + i) * 4 + 1], hg.y, acc[jr]);
                acc[jr] = dot2(wreg[(jr * 4 + i) * 4 + 2], hg.z, acc[jr]);
                acc[jr] = dot2(wreg[(jr * 4 + i) * 4 + 3], hg.w, acc[jr]);
            }
#pragma unroll
            for (int js = 0; js < 4; ++js) {
                uint4 w = wlds[(js * 4 + i) * 512 + tid];
                acc[12 + js] = dot2(w.x, hg.x, acc[12 + js]);
                acc[12 + js] = dot2(w.y, hg.y, acc[12 + js]);
                acc[12 + js] = dot2(w.z, hg.z, acc[12 + js]);
                acc[12 + js] = dot2(w.w, hg.w, acc[12 + js]);
            }
        }
        float s, keep;
#define FOLD_DPP(aL, aH, bit, ctrl, dst)                                      \
        s = (c & bit) ? (aL) : (aH);                                          \
        s = __builtin_bit_cast(float, __builtin_amdgcn_mov_dpp(               \
                __builtin_bit_cast(int, s), ctrl, 0xF, 0xF, true));           \
        keep = (c & bit) ? (aH) : (aL);                                       \
        dst = keep + s;
#define FOLD_SWZ(aL, aH, bit, pat, dst)                                       \
        s = (c & bit) ? (aL) : (aH);                                          \
        s = __builtin_bit_cast(float, __builtin_amdgcn_ds_swizzle(            \
                __builtin_bit_cast(int, s), pat));                            \
        keep = (c & bit) ? (aH) : (aL);                                       \
        dst = keep + s;
        float b0, b1, b2, b3, b4, b5, b6, b7, d0, d1, d2, d3, e0, e1, v;
        FOLD_DPP(acc[0],  acc[1],  1, 0xB1, b0)
        FOLD_DPP(acc[2],  acc[3],  1, 0xB1, b1)
        FOLD_DPP(acc[4],  acc[5],  1, 0xB1, b2)
        FOLD_DPP(acc[6],  acc[7],  1, 0xB1, b3)
        FOLD_DPP(acc[8],  acc[9],  1, 0xB1, b4)
        FOLD_DPP(acc[10], acc[11], 1, 0xB1, b5)
        FOLD_DPP(acc[12], acc[13], 1, 0xB1, b6)
        FOLD_DPP(acc[14], acc[15], 1, 0xB1, b7)
        FOLD_DPP(b0, b1, 2, 0x4E, d0)
        FOLD_DPP(b2, b3, 2, 0x4E, d1)
        FOLD_DPP(b4, b5, 2, 0x4E, d2)
        FOLD_DPP(b6, b7, 2, 0x4E, d3)
        FOLD_DPP(d0, d2, 8, 0x128, e0)
        FOLD_DPP(d1, d3, 8, 0x128, e1)
        FOLD_SWZ(e0, e1, 4, 0x101F, v)
#undef FOLD_DPP
#undef FOLD_SWZ
        float hnew = fast_tanh(v + zv);
        _Float16 h16v = (_Float16)hnew;
        ((_Float16*)hbuf4)[(cur ^ 1) * 512 + hstore] = h16v;
        if (hs_out) hs_out[t * HDIM + tid] = h16v;
        hlast = h16v;
        __syncthreads();
        // barrier drained vmcnt(0): h16 rows <= t are in this XCD's L2.
        // Push L2 -> L3 (device-visible) and publish progress (agent scope).
        if (prog && (t & 127) == 127 && tid == 0) {
            __threadfence();
            __hip_atomic_store(prog, t + 1, __ATOMIC_RELEASE,
                               __HIP_MEMORY_SCOPE_AGENT);
        }
        cur ^= 1;
    }
    if (hfin_out) hfin_out[tid] = hlast;
}

// ---------------------------------------------------------------------------
// prep_a: zero progress flag + pack enc_whh + zker for encoder steps.
// blocks [0,128): pack; blocks [128,640): zker t in [0,512).
// ---------------------------------------------------------------------------
__global__ void __launch_bounds__(256) prep_a(
    const float* __restrict__ enc_whh, _Float16* __restrict__ wpe,
    const int* __restrict__ in_ids, const float* __restrict__ emb,
    const float* __restrict__ enc_wih, const float* __restrict__ enc_bih,
    const float* __restrict__ enc_bhh, float* __restrict__ z,
    int* __restrict__ prog) {
    __shared__ float x[EDIM];
    int b = blockIdx.x;
    if (b == 0 && threadIdx.x == 0)
        __hip_atomic_store(prog, 0, __ATOMIC_RELAXED, __HIP_MEMORY_SCOPE_AGENT);
    if (b < 128) {
        int idx = b * 256 + threadIdx.x;           // 0..32767
        int g = idx >> 9, t = idx & 511;
        int jr = g >> 2, i = g & 3;
        int row = ((t >> 4) << 4) + jr;
        int k0 = ((t & 15) << 5) + (i << 3);
        const float* src = enc_whh + row * HDIM + k0;
        uint32_t d[4];
#pragma unroll
        for (int q = 0; q < 4; ++q) {
            half2_t p;
            p[0] = (_Float16)src[2 * q];
            p[1] = (_Float16)src[2 * q + 1];
            d[q] = __builtin_bit_cast(uint32_t, p);
        }
        ((uint4*)wpe)[g * 512 + t] = make_uint4(d[0], d[1], d[2], d[3]);
    } else {
        int t = b - 128;                           // 0..511
        int id = in_ids[t];
        x[threadIdx.x] = emb[(long)id * EDIM + threadIdx.x];
        __syncthreads();
#pragma unroll
        for (int rr = 0; rr < 2; ++rr) {
            int r = threadIdx.x + rr * 256;
            const float4* w4 = (const float4*)(enc_wih + r * EDIM);
            float acc = 0.f;
#pragma unroll 8
            for (int k4 = 0; k4 < 64; ++k4) {
                float4 wv = w4[k4];
                acc += wv.x * x[k4 * 4 + 0] + wv.y * x[k4 * 4 + 1] +
                       wv.z * x[k4 * 4 + 2] + wv.w * x[k4 * 4 + 3];
            }
            z[t * HDIM + r] = acc + enc_bih[r] + enc_bhh[r];
        }
    }
}

// ---------------------------------------------------------------------------
// enc_fused: block 0 = ENCODER scan (712 us, 1 CU). All other blocks do the
// independent prep that used to run serially: pack dec_whh (64 blocks),
// zker for decoder steps (512 blocks), fc_w f32->f16 (rest) — all hidden
// under the scan on the other 255 CUs.
// ---------------------------------------------------------------------------
__global__ void __launch_bounds__(512, 2) enc_fused(
    const _Float16* __restrict__ wpe, const float* __restrict__ z,
    _Float16* __restrict__ hn16,
    const float* __restrict__ dec_whh, _Float16* __restrict__ wpd,
    const int* __restrict__ out_ids, const float* __restrict__ emb,
    const float* __restrict__ dec_wih, const float* __restrict__ dec_bih,
    const float* __restrict__ dec_bhh, float* __restrict__ zf,
    const float* __restrict__ fc_w, _Float16* __restrict__ fcw16, long fcw_n) {
    __shared__ uint4 wlds[16 * 512];   // 128 KB (scan); reused as x[] by zker
    __shared__ uint4 hbuf4[2 * 64];
    int b = blockIdx.x, tid = threadIdx.x;
    if (b == 0) {
        scan_body(wpe, z, nullptr, nullptr, hn16, nullptr, 512, wlds, hbuf4);
    } else if (b < 65) {
        // pack dec_whh
        int idx = (b - 1) * 512 + tid;             // 0..32767
        int g = idx >> 9, t = idx & 511;
        int jr = g >> 2, i = g & 3;
        int row = ((t >> 4) << 4) + jr;
        int k0 = ((t & 15) << 5) + (i << 3);
        const float* src = dec_whh + row * HDIM + k0;
        uint32_t d[4];
#pragma unroll
        for (int q = 0; q < 4; ++q) {
            half2_t p;
            p[0] = (_Float16)src[2 * q];
            p[1] = (_Float16)src[2 * q + 1];
            d[q] = __builtin_bit_cast(uint32_t, p);
        }
        ((uint4*)wpd)[g * 512 + t] = make_uint4(d[0], d[1], d[2], d[3]);
    } else if (b < 577) {
        // zker decoder: t in [512, 1024), 512 threads = 1 row each
        int t = 512 + (b - 65);
        float* x = (float*)wlds;
        int id = (t == 512) ? 1 : out_ids[t - 513];
        if (tid < EDIM) x[tid] = emb[(long)id * EDIM + tid];
        __syncthreads();
        const float4* w4 = (const float4*)(dec_wih + tid * EDIM);
        float acc = 0.f;
#pragma unroll 8
        for (int k4 = 0; k4 < 64; ++k4) {
            float4 wv = w4[k4];
            acc += wv.x * x[k4 * 4 + 0] + wv.y * x[k4 * 4 + 1] +
                   wv.z * x[k4 * 4 + 2] + wv.w * x[k4 * 4 + 3];
        }
        zf[t * HDIM + tid] = acc + dec_bih[tid] + dec_bhh[tid];
    } else {
        // cvt fc_w -> f16
        long i = ((long)(b - 577) * 512 + tid) * 8;
        if (i + 8 <= fcw_n) {
            const float4* s4 = (const float4*)(fc_w + i);
            float4 a = s4[0], bb = s4[1];
            half8_t o;
            o[0] = (_Float16)a.x;  o[1] = (_Float16)a.y;
            o[2] = (_Float16)a.z;  o[3] = (_Float16)a.w;
            o[4] = (_Float16)bb.x; o[5] = (_Float16)bb.y;
            o[6] = (_Float16)bb.z; o[7] = (_Float16)bb.w;
            *(half8_t*)(fcw16 + i) = o;
        }
    }
}

// ---------------------------------------------------------------------------
// dec_fc: block 0 = DECODER scan publishing progress every 128 steps.
// Blocks 1..255 = FC consumers, grid-striding NJOBS jobs in m-major order
// (job j: m-tile = j/NT_FC unlocks at decoder step (m+1)*128). Each job:
// acquire progress flag -> __threadfence (invalidate local L1/L2; XCD L2s
// are NOT coherent) -> compute 128m x 256n tile with f16 MFMA.
// Deadlock-free: 256 blocks x 130KB LDS = 1 block/CU, all co-resident;
// block 0 never waits.
// ---------------------------------------------------------------------------
__global__ void __launch_bounds__(512, 2) dec_fc(
    const _Float16* __restrict__ wpd, const float* __restrict__ zdec,
    const _Float16* __restrict__ hn16, _Float16* __restrict__ h16,
    int* __restrict__ prog,
    const _Float16* __restrict__ Bw16, const float* __restrict__ Bw32,
    int use16, const float* __restrict__ bias, float* __restrict__ out) {
    __shared__ uint4 wlds[16 * 512];
    __shared__ uint4 hbuf4[2 * 64];
    int b = blockIdx.x, tid = threadIdx.x;
    if (b == 0) {
        scan_body(wpd, zdec, hn16, h16, nullptr, prog, 512, wlds, hbuf4);
        return;
    }
    int w = tid >> 6, l = tid & 63;
    int wm = (w >> 2) * 64, wn = (w & 3) * 64;
    int lr = l & 15, lk = (l >> 4) * 8;
    for (int j = b - 1; j < NJOBS; j += 255) {
        int mj = j / NT_FC, nj = j - mj * NT_FC;
        if (tid == 0) {
            int need = (mj + 1) * 128;
            while (__hip_atomic_load(prog, __ATOMIC_ACQUIRE,
                                     __HIP_MEMORY_SCOPE_AGENT) < need)
                __builtin_amdgcn_s_sleep(16);
            __threadfence();   // invalidate stale L1/L2 before reading h16
        }
        __syncthreads();
        int m0 = mj * 128, n0 = nj * 256;
        float4_t acc[4][4];
#pragma unroll
        for (int fm = 0; fm < 4; ++fm)
#pragma unroll
            for (int fn = 0; fn < 4; ++fn)
                acc[fm][fn] = (float4_t){0.f, 0.f, 0.f, 0.f};
        for (int ks = 0; ks < 512; ks += 32) {
            half8_t a[4], bf[4];
#pragma unroll
            for (int f = 0; f < 4; ++f) {
                int m = m0 + wm + f * 16 + lr;
                a[f] = *(const half8_t*)(h16 + (long)m * 512 + ks + lk);
                int n = n0 + wn + f * 16 + lr;
                if (n < CDIM) {
                    if (use16) {
                        bf[f] = *(const half8_t*)(Bw16 + (long)n * 512 + ks + lk);
                    } else {
                        const float4* bp4 =
                            (const float4*)(Bw32 + (long)n * 512 + ks + lk);
                        float4 x0 = bp4[0], x1 = bp4[1];
                        half8_t bb;
                        bb[0] = (_Float16)x0.x; bb[1] = (_Float16)x0.y;
                        bb[2] = (_Float16)x0.z; bb[3] = (_Float16)x0.w;
                        bb[4] = (_Float16)x1.x; bb[5] = (_Float16)x1.y;
                        bb[6] = (_Float16)x1.z; bb[7] = (_Float16)x1.w;
                        bf[f] = bb;
                    }
                } else {
#pragma unroll
                    for (int e = 0; e < 8; ++e) bf[f][e] = (_Float16)0.f;
                }
            }
#pragma unroll
            for (int fm = 0; fm < 4; ++fm)
#pragma unroll
                for (int fn = 0; fn < 4; ++fn)
                    acc[fm][fn] = __builtin_amdgcn_mfma_f32_16x16x32_f16(
                        a[fm], bf[fn], acc[fm][fn], 0, 0, 0);
        }
#pragma unroll
        for (int fn = 0; fn < 4; ++fn) {
            int n = n0 + wn + fn * 16 + lr;
            if (n >= CDIM) continue;
            float bv = bias[n];
#pragma unroll
            for (int fm = 0; fm < 4; ++fm) {
#pragma unroll
                for (int q = 0; q < 4; ++q) {
                    int m = m0 + wm + fm * 16 + (l >> 4) * 4 + q;
                    out[(long)m * CDIM + n] = acc[fm][fn][q] + bv;
                }
            }
        }
    }
}

// ---------------------------------------------------------------------------
// Workspace layout:
//   [0, 2MB)            z  f32 [1024][512]
//   [2MB, 2.5MB)        wpack_enc f16
//   [2.5MB, 3MB)        wpack_dec f16
//   [3MB, 3.5MB)        h16 f16 [512][512]
//   [3.5MB, +1KB)       hn16 f16 [512]
//   [3.5MB+1KB, +4B)    progress flag (int)
//   [4MB, 4MB+51.5MB)   fc_w16 (only if ws_size permits)
// ---------------------------------------------------------------------------
extern "C" void kernel_launch(void* const* d_in, const int* in_sizes, int n_in,
                              void* d_out, int out_size, void* d_ws, size_t ws_size,
                              hipStream_t stream) {
    const int* input_ids  = (const int*)d_in[1];
    const int* output_ids = (const int*)d_in[2];
    const float* emb      = (const float*)d_in[3];
    const float* enc_wih  = (const float*)d_in[4];
    const float* enc_whh  = (const float*)d_in[5];
    const float* enc_bih  = (const float*)d_in[6];
    const float* enc_bhh  = (const float*)d_in[7];
    const float* dec_wih  = (const float*)d_in[8];
    const float* dec_whh  = (const float*)d_in[9];
    const float* dec_bih  = (const float*)d_in[10];
    const float* dec_bhh  = (const float*)d_in[11];
    const float* fc_w     = (const float*)d_in[12];
    const float* fc_b     = (const float*)d_in[13];
    float* out = (float*)d_out;

    char* ws = (char*)d_ws;
    float* z        = (float*)ws;                                  // 2 MB
    _Float16* wpe   = (_Float16*)(ws + (2u << 20));                // 512 KB
    _Float16* wpd   = (_Float16*)(ws + (2u << 20) + (512u << 10)); // 512 KB
    _Float16* h16   = (_Float16*)(ws + (3u << 20));                // 512 KB
    _Float16* hn16  = (_Float16*)(ws + (3u << 20) + (512u << 10)); // 1 KB
    int* prog       = (int*)(ws + (3u << 20) + (513u << 10));      // 4 B
    _Float16* fcw16 = (_Float16*)(ws + (4u << 20));                // 51.5 MB

    const long fcw_n = (long)CDIM * HDIM;
    bool use_f16_fc = ws_size >= (size_t)(4u << 20) + (size_t)fcw_n * 2;
    int nb_cvt = use_f16_fc ? (int)((fcw_n / 8 + 511) / 512) : 0;

    // 1: zero progress + pack enc + encoder z
    prep_a<<<640, 256, 0, stream>>>(enc_whh, wpe, input_ids, emb,
                                    enc_wih, enc_bih, enc_bhh, z, prog);
    // 2: encoder scan (block 0) || pack dec + decoder z + fc_w cvt
    enc_fused<<<577 + nb_cvt, 512, 0, stream>>>(
        wpe, z, hn16, dec_whh, wpd, output_ids, emb,
        dec_wih, dec_bih, dec_bhh, z, fc_w, fcw16, fcw_n);
    // 3: decoder scan (block 0, publishes progress) || FC consumers
    dec_fc<<<256, 512, 0, stream>>>(wpd, z + 512 * HDIM, hn16, h16, prog,
                                    fcw16, fc_w, use_f16_fc ? 1 : 0,
                                    fc_b, out);
}

// Round 12
// 1491.557 us; speedup vs baseline: 12.1594x; 1.1003x over previous
//
#include <hip/hip_runtime.h>
#include <hip/hip_fp16.h>

#define EDIM 256
#define HDIM 512
#define CDIM 50257
#define NT_FC 197                 // ceil(50257 / 256) n-tiles
#define NJOBS (NT_FC * 4)         // x 4 m-tiles

using half2_t = __attribute__((ext_vector_type(2))) _Float16;
using half8_t = __attribute__((ext_vector_type(8))) _Float16;
using float4_t = __attribute__((ext_vector_type(4))) float;

__device__ __forceinline__ float dot2(uint32_t w, uint32_t h, float acc) {
    return __builtin_amdgcn_fdot2(__builtin_bit_cast(half2_t, w),
                                  __builtin_bit_cast(half2_t, h), acc, false);
}

// tanh(x) = 1 - 2/(exp2(2x*log2e)+1)
__device__ __forceinline__ float fast_tanh(float x) {
    float e = __builtin_amdgcn_exp2f(x * 2.8853900817779268f);
    return 1.f - 2.f * __builtin_amdgcn_rcpf(e + 1.f);
}

// ---------------------------------------------------------------------------
// R6-validated scan body (709-712 us/scan, 5 rounds stable). Thread t:
// rg = t>>4 owns rows [rg*16,+16), c = t&15 owns k-slice [c*32,+32).
// 12/16 rows register-resident, 4/16 streamed from LDS (128 KB). h f16 in
// LDS, double-buffered, [i][c] granule layout. Folds: xor1/xor2 DPP
// quad_perm, xor8 DPP row_ror:8, xor4 ds_swizzle. One barrier/step.
// Progress publication every 128 steps (agent-scope release) so consumer
// blocks in the SAME kernel can start FC on finished h16 rows.
// ---------------------------------------------------------------------------
__device__ __forceinline__ void scan_body(
    const _Float16* __restrict__ wpack, const float* __restrict__ z,
    const _Float16* __restrict__ h_init, _Float16* __restrict__ hs_out,
    _Float16* __restrict__ hfin_out, int* prog, int nsteps,
    uint4* wlds, uint4* hbuf4) {
    const int tid = threadIdx.x;
    const int c = tid & 15;
    const int g_own = tid >> 3;
    const int hstore = 128 * (g_own & 3) + 8 * (g_own >> 2) + (tid & 7);

    const uint4* wp4 = (const uint4*)wpack;
    uint32_t wreg[192];                // rows jr=0..11
#pragma unroll
    for (int g = 0; g < 48; ++g) {
        uint4 v = wp4[g * 512 + tid];
        wreg[g * 4 + 0] = v.x; wreg[g * 4 + 1] = v.y;
        wreg[g * 4 + 2] = v.z; wreg[g * 4 + 3] = v.w;
    }
#pragma unroll
    for (int g = 48; g < 64; ++g) wlds[(g - 48) * 512 + tid] = wp4[g * 512 + tid];

    ((_Float16*)hbuf4)[hstore] = h_init ? h_init[tid] : (_Float16)0.f;
    __syncthreads();

    _Float16 hlast = (_Float16)0.f;
    int cur = 0;
    for (int t = 0; t < nsteps; ++t) {
        float zv = z[t * HDIM + tid];
        const uint4* hb = hbuf4 + cur * 64;
        float acc[16];
#pragma unroll
        for (int r = 0; r < 16; ++r) acc[r] = 0.f;
#pragma unroll
        for (int i = 0; i < 4; ++i) {
            uint4 hg = hb[i * 16 + c];
#pragma unroll
            for (int jr = 0; jr < 12; ++jr) {
                acc[jr] = dot2(wreg[(jr * 4 + i) * 4 + 0], hg.x, acc[jr]);
                acc[jr] = dot2(wreg[(jr * 4 + i) * 4 + 1], hg.y, acc[jr]);
                acc[jr] = dot2(wreg[(jr * 4 + i) * 4 + 2], hg.z, acc[jr]);
                acc[jr] = dot2(wreg[(jr * 4 + i) * 4 + 3], hg.w, acc[jr]);
            }
#pragma unroll
            for (int js = 0; js < 4; ++js) {
                uint4 w = wlds[(js * 4 + i) * 512 + tid];
                acc[12 + js] = dot2(w.x, hg.x, acc[12 + js]);
                acc[12 + js] = dot2(w.y, hg.y, acc[12 + js]);
                acc[12 + js] = dot2(w.z, hg.z, acc[12 + js]);
                acc[12 + js] = dot2(w.w, hg.w, acc[12 + js]);
            }
        }
        float s, keep;
#define FOLD_DPP(aL, aH, bit, ctrl, dst)                                      \
        s = (c & bit) ? (aL) : (aH);                                          \
        s = __builtin_bit_cast(float, __builtin_amdgcn_mov_dpp(               \
                __builtin_bit_cast(int, s), ctrl, 0xF, 0xF, true));           \
        keep = (c & bit) ? (aH) : (aL);                                       \
        dst = keep + s;
#define FOLD_SWZ(aL, aH, bit, pat, dst)                                       \
        s = (c & bit) ? (aL) : (aH);                                          \
        s = __builtin_bit_cast(float, __builtin_amdgcn_ds_swizzle(            \
                __builtin_bit_cast(int, s), pat));                            \
        keep = (c & bit) ? (aH) : (aL);                                       \
        dst = keep + s;
        float b0, b1, b2, b3, b4, b5, b6, b7, d0, d1, d2, d3, e0, e1, v;
        FOLD_DPP(acc[0],  acc[1],  1, 0xB1, b0)
        FOLD_DPP(acc[2],  acc[3],  1, 0xB1, b1)
        FOLD_DPP(acc[4],  acc[5],  1, 0xB1, b2)
        FOLD_DPP(acc[6],  acc[7],  1, 0xB1, b3)
        FOLD_DPP(acc[8],  acc[9],  1, 0xB1, b4)
        FOLD_DPP(acc[10], acc[11], 1, 0xB1, b5)
        FOLD_DPP(acc[12], acc[13], 1, 0xB1, b6)
        FOLD_DPP(acc[14], acc[15], 1, 0xB1, b7)
        FOLD_DPP(b0, b1, 2, 0x4E, d0)
        FOLD_DPP(b2, b3, 2, 0x4E, d1)
        FOLD_DPP(b4, b5, 2, 0x4E, d2)
        FOLD_DPP(b6, b7, 2, 0x4E, d3)
        FOLD_DPP(d0, d2, 8, 0x128, e0)
        FOLD_DPP(d1, d3, 8, 0x128, e1)
        FOLD_SWZ(e0, e1, 4, 0x101F, v)
#undef FOLD_DPP
#undef FOLD_SWZ
        float hnew = fast_tanh(v + zv);
        _Float16 h16v = (_Float16)hnew;
        ((_Float16*)hbuf4)[(cur ^ 1) * 512 + hstore] = h16v;
        if (hs_out) hs_out[t * HDIM + tid] = h16v;
        hlast = h16v;
        __syncthreads();
        // barrier drained vmcnt(0): h16 rows <= t are in this XCD's L2.
        // Push L2 -> L3 (device-visible) and publish progress (agent scope).
        if (prog && (t & 127) == 127 && tid == 0) {
            __threadfence();
            __hip_atomic_store(prog, t + 1, __ATOMIC_RELEASE,
                               __HIP_MEMORY_SCOPE_AGENT);
        }
        cur ^= 1;
    }
    if (hfin_out) hfin_out[tid] = hlast;
}

// ---------------------------------------------------------------------------
// prep_a: zero progress flag + pack enc_whh + zker for encoder steps.
// blocks [0,128): pack; blocks [128,640): zker t in [0,512).
// ---------------------------------------------------------------------------
__global__ void __launch_bounds__(256) prep_a(
    const float* __restrict__ enc_whh, _Float16* __restrict__ wpe,
    const int* __restrict__ in_ids, const float* __restrict__ emb,
    const float* __restrict__ enc_wih, const float* __restrict__ enc_bih,
    const float* __restrict__ enc_bhh, float* __restrict__ z,
    int* __restrict__ prog) {
    __shared__ float x[EDIM];
    int b = blockIdx.x;
    if (b == 0 && threadIdx.x == 0)
        __hip_atomic_store(prog, 0, __ATOMIC_RELAXED, __HIP_MEMORY_SCOPE_AGENT);
    if (b < 128) {
        int idx = b * 256 + threadIdx.x;           // 0..32767
        int g = idx >> 9, t = idx & 511;
        int jr = g >> 2, i = g & 3;
        int row = ((t >> 4) << 4) + jr;
        int k0 = ((t & 15) << 5) + (i << 3);
        const float* src = enc_whh + row * HDIM + k0;
        uint32_t d[4];
#pragma unroll
        for (int q = 0; q < 4; ++q) {
            half2_t p;
            p[0] = (_Float16)src[2 * q];
            p[1] = (_Float16)src[2 * q + 1];
            d[q] = __builtin_bit_cast(uint32_t, p);
        }
        ((uint4*)wpe)[g * 512 + t] = make_uint4(d[0], d[1], d[2], d[3]);
    } else {
        int t = b - 128;                           // 0..511
        int id = in_ids[t];
        x[threadIdx.x] = emb[(long)id * EDIM + threadIdx.x];
        __syncthreads();
#pragma unroll
        for (int rr = 0; rr < 2; ++rr) {
            int r = threadIdx.x + rr * 256;
            const float4* w4 = (const float4*)(enc_wih + r * EDIM);
            float acc = 0.f;
#pragma unroll 8
            for (int k4 = 0; k4 < 64; ++k4) {
                float4 wv = w4[k4];
                acc += wv.x * x[k4 * 4 + 0] + wv.y * x[k4 * 4 + 1] +
                       wv.z * x[k4 * 4 + 2] + wv.w * x[k4 * 4 + 3];
            }
            z[t * HDIM + r] = acc + enc_bih[r] + enc_bhh[r];
        }
    }
}

// ---------------------------------------------------------------------------
// enc_fused: block 0 = ENCODER scan (1 CU). All other blocks do the
// independent prep hidden under the scan: pack dec_whh (64 blocks),
// zker decoder steps (512 blocks), fc_w f32->f16 (rest).
// ---------------------------------------------------------------------------
__global__ void __launch_bounds__(512, 2) enc_fused(
    const _Float16* __restrict__ wpe, const float* __restrict__ z,
    _Float16* __restrict__ hn16,
    const float* __restrict__ dec_whh, _Float16* __restrict__ wpd,
    const int* __restrict__ out_ids, const float* __restrict__ emb,
    const float* __restrict__ dec_wih, const float* __restrict__ dec_bih,
    const float* __restrict__ dec_bhh, float* __restrict__ zf,
    const float* __restrict__ fc_w, _Float16* __restrict__ fcw16, long fcw_n) {
    __shared__ uint4 wlds[16 * 512];   // 128 KB (scan); reused as x[] by zker
    __shared__ uint4 hbuf4[2 * 64];
    int b = blockIdx.x, tid = threadIdx.x;
    if (b == 0) {
        scan_body(wpe, z, nullptr, nullptr, hn16, nullptr, 512, wlds, hbuf4);
    } else if (b < 65) {
        // pack dec_whh
        int idx = (b - 1) * 512 + tid;             // 0..32767
        int g = idx >> 9, t = idx & 511;
        int jr = g >> 2, i = g & 3;
        int row = ((t >> 4) << 4) + jr;
        int k0 = ((t & 15) << 5) + (i << 3);
        const float* src = dec_whh + row * HDIM + k0;
        uint32_t d[4];
#pragma unroll
        for (int q = 0; q < 4; ++q) {
            half2_t p;
            p[0] = (_Float16)src[2 * q];
            p[1] = (_Float16)src[2 * q + 1];
            d[q] = __builtin_bit_cast(uint32_t, p);
        }
        ((uint4*)wpd)[g * 512 + t] = make_uint4(d[0], d[1], d[2], d[3]);
    } else if (b < 577) {
        // zker decoder: t in [512, 1024), 512 threads = 1 row each
        int t = 512 + (b - 65);
        float* x = (float*)wlds;
        int id = (t == 512) ? 1 : out_ids[t - 513];
        if (tid < EDIM) x[tid] = emb[(long)id * EDIM + tid];
        __syncthreads();
        const float4* w4 = (const float4*)(dec_wih + tid * EDIM);
        float acc = 0.f;
#pragma unroll 8
        for (int k4 = 0; k4 < 64; ++k4) {
            float4 wv = w4[k4];
            acc += wv.x * x[k4 * 4 + 0] + wv.y * x[k4 * 4 + 1] +
                   wv.z * x[k4 * 4 + 2] + wv.w * x[k4 * 4 + 3];
        }
        zf[t * HDIM + tid] = acc + dec_bih[tid] + dec_bhh[tid];
    } else {
        // cvt fc_w -> f16
        long i = ((long)(b - 577) * 512 + tid) * 8;
        if (i + 8 <= fcw_n) {
            const float4* s4 = (const float4*)(fc_w + i);
            float4 a = s4[0], bb = s4[1];
            half8_t o;
            o[0] = (_Float16)a.x;  o[1] = (_Float16)a.y;
            o[2] = (_Float16)a.z;  o[3] = (_Float16)a.w;
            o[4] = (_Float16)bb.x; o[5] = (_Float16)bb.y;
            o[6] = (_Float16)bb.z; o[7] = (_Float16)bb.w;
            *(half8_t*)(fcw16 + i) = o;
        }
    }
}

// ---------------------------------------------------------------------------
// dec_fc: block 0 = DECODER scan publishing progress every 128 steps.
// Blocks 1..255 = FC consumers, grid-striding NJOBS jobs m-major.
// R12 FIX: spin on a RELAXED agent-scope load (visibility guaranteed by
// scope; no per-poll cache invalidate — R11's ACQUIRE spin emitted an L1/L2
// invalidate per poll, ~32 blocks/XCD thrashed every XCD's caches and cost
// the scan ~1100 cyc/step in I-fetch/L2 misses). ONE __threadfence after the
// wait succeeds invalidates stale L1/L2 before reading fresh h16 (XCD L2s
// are NOT coherent). s_sleep 64 (~1.7us poll) cuts poll traffic 4x.
// Deadlock-free: 256 blocks x 130KB LDS = 1 block/CU, all co-resident;
// block 0 never waits.
// ---------------------------------------------------------------------------
__global__ void __launch_bounds__(512, 2) dec_fc(
    const _Float16* __restrict__ wpd, const float* __restrict__ zdec,
    const _Float16* __restrict__ hn16, _Float16* __restrict__ h16,
    int* __restrict__ prog,
    const _Float16* __restrict__ Bw16, const float* __restrict__ Bw32,
    int use16, const float* __restrict__ bias, float* __restrict__ out) {
    __shared__ uint4 wlds[16 * 512];
    __shared__ uint4 hbuf4[2 * 64];
    int b = blockIdx.x, tid = threadIdx.x;
    if (b == 0) {
        scan_body(wpd, zdec, hn16, h16, nullptr, prog, 512, wlds, hbuf4);
        return;
    }
    int w = tid >> 6, l = tid & 63;
    int wm = (w >> 2) * 64, wn = (w & 3) * 64;
    int lr = l & 15, lk = (l >> 4) * 8;
    for (int j = b - 1; j < NJOBS; j += 255) {
        int mj = j / NT_FC, nj = j - mj * NT_FC;
        if (tid == 0) {
            int need = (mj + 1) * 128;
            while (__hip_atomic_load(prog, __ATOMIC_RELAXED,
                                     __HIP_MEMORY_SCOPE_AGENT) < need)
                __builtin_amdgcn_s_sleep(64);
            __threadfence();   // one-time invalidate before reading h16
        }
        __syncthreads();
        int m0 = mj * 128, n0 = nj * 256;
        float4_t acc[4][4];
#pragma unroll
        for (int fm = 0; fm < 4; ++fm)
#pragma unroll
            for (int fn = 0; fn < 4; ++fn)
                acc[fm][fn] = (float4_t){0.f, 0.f, 0.f, 0.f};
        for (int ks = 0; ks < 512; ks += 32) {
            half8_t a[4], bf[4];
#pragma unroll
            for (int f = 0; f < 4; ++f) {
                int m = m0 + wm + f * 16 + lr;
                a[f] = *(const half8_t*)(h16 + (long)m * 512 + ks + lk);
                int n = n0 + wn + f * 16 + lr;
                if (n < CDIM) {
                    if (use16) {
                        bf[f] = *(const half8_t*)(Bw16 + (long)n * 512 + ks + lk);
                    } else {
                        const float4* bp4 =
                            (const float4*)(Bw32 + (long)n * 512 + ks + lk);
                        float4 x0 = bp4[0], x1 = bp4[1];
                        half8_t bb;
                        bb[0] = (_Float16)x0.x; bb[1] = (_Float16)x0.y;
                        bb[2] = (_Float16)x0.z; bb[3] = (_Float16)x0.w;
                        bb[4] = (_Float16)x1.x; bb[5] = (_Float16)x1.y;
                        bb[6] = (_Float16)x1.z; bb[7] = (_Float16)x1.w;
                        bf[f] = bb;
                    }
                } else {
#pragma unroll
                    for (int e = 0; e < 8; ++e) bf[f][e] = (_Float16)0.f;
                }
            }
#pragma unroll
            for (int fm = 0; fm < 4; ++fm)
#pragma unroll
                for (int fn = 0; fn < 4; ++fn)
                    acc[fm][fn] = __builtin_amdgcn_mfma_f32_16x16x32_f16(
                        a[fm], bf[fn], acc[fm][fn], 0, 0, 0);
        }
#pragma unroll
        for (int fn = 0; fn < 4; ++fn) {
            int n = n0 + wn + fn * 16 + lr;
            if (n >= CDIM) continue;
            float bv = bias[n];
#pragma unroll
            for (int fm = 0; fm < 4; ++fm) {
#pragma unroll
                for (int q = 0; q < 4; ++q) {
                    int m = m0 + wm + fm * 16 + (l >> 4) * 4 + q;
                    out[(long)m * CDIM + n] = acc[fm][fn][q] + bv;
                }
            }
        }
    }
}

// ---------------------------------------------------------------------------
// Workspace layout:
//   [0, 2MB)            z  f32 [1024][512]
//   [2MB, 2.5MB)        wpack_enc f16
//   [2.5MB, 3MB)        wpack_dec f16
//   [3MB, 3.5MB)        h16 f16 [512][512]
//   [3.5MB, +1KB)       hn16 f16 [512]
//   [3.5MB+1KB, +4B)    progress flag (int)
//   [4MB, 4MB+51.5MB)   fc_w16 (only if ws_size permits)
// ---------------------------------------------------------------------------
extern "C" void kernel_launch(void* const* d_in, const int* in_sizes, int n_in,
                              void* d_out, int out_size, void* d_ws, size_t ws_size,
                              hipStream_t stream) {
    const int* input_ids  = (const int*)d_in[1];
    const int* output_ids = (const int*)d_in[2];
    const float* emb      = (const float*)d_in[3];
    const float* enc_wih  = (const float*)d_in[4];
    const float* enc_whh  = (const float*)d_in[5];
    const float* enc_bih  = (const float*)d_in[6];
    const float* enc_bhh  = (const float*)d_in[7];
    const float* dec_wih  = (const float*)d_in[8];
    const float* dec_whh  = (const float*)d_in[9];
    const float* dec_bih  = (const float*)d_in[10];
    const float* dec_bhh  = (const float*)d_in[11];
    const float* fc_w     = (const float*)d_in[12];
    const float* fc_b     = (const float*)d_in[13];
    float* out = (float*)d_out;

    char* ws = (char*)d_ws;
    float* z        = (float*)ws;                                  // 2 MB
    _Float16* wpe   = (_Float16*)(ws + (2u << 20));                // 512 KB
    _Float16* wpd   = (_Float16*)(ws + (2u << 20) + (512u << 10)); // 512 KB
    _Float16* h16   = (_Float16*)(ws + (3u << 20));                // 512 KB
    _Float16* hn16  = (_Float16*)(ws + (3u << 20) + (512u << 10)); // 1 KB
    int* prog       = (int*)(ws + (3u << 20) + (513u << 10));      // 4 B
    _Float16* fcw16 = (_Float16*)(ws + (4u << 20));                // 51.5 MB

    const long fcw_n = (long)CDIM * HDIM;
    bool use_f16_fc = ws_size >= (size_t)(4u << 20) + (size_t)fcw_n * 2;
    int nb_cvt = use_f16_fc ? (int)((fcw_n / 8 + 511) / 512) : 0;

    // 1: zero progress + pack enc + encoder z
    prep_a<<<640, 256, 0, stream>>>(enc_whh, wpe, input_ids, emb,
                                    enc_wih, enc_bih, enc_bhh, z, prog);
    // 2: encoder scan (block 0) || pack dec + decoder z + fc_w cvt
    enc_fused<<<577 + nb_cvt, 512, 0, stream>>>(
        wpe, z, hn16, dec_whh, wpd, output_ids, emb,
        dec_wih, dec_bih, dec_bhh, z, fc_w, fcw16, fcw_n);
    // 3: decoder scan (block 0, publishes progress) || FC consumers
    dec_fc<<<256, 512, 0, stream>>>(wpd, z + 512 * HDIM, hn16, h16, prog,
                                    fcw16, fc_w, use_f16_fc ? 1 : 0,
                                    fc_b, out);
}